// Round 1
// baseline (110.838 us; speedup 1.0000x reference)
//
#include <hip/hip_runtime.h>
#include <hip/hip_bf16.h>

// Problem constants (fixed shapes from setup_inputs)
constexpr int NPTS = 16384;   // points per batch
constexpr int NCTR = 2048;    // centers per batch
constexpr int NCH  = 64;      // feature channels
constexpr int KK   = 32;      // neighbors per center
constexpr int NB   = 2;       // batches
// radius^2: reference compares d2 < fp32(0.04) (python double 0.2*0.2 -> f32)
#define R2 0.04f

// -------- Kernel 1: transpose features (b,64,16384) -> (b,16384,64) --------
__global__ __launch_bounds__(256) void transpose_feats(
    const float* __restrict__ f, float* __restrict__ ft)
{
    __shared__ float tile[64][65];   // +1 pad: conflict-free transpose
    const int b  = blockIdx.y;
    const int n0 = blockIdx.x * 64;
    const int t  = threadIdx.x;
    const int nl = t & 63;           // fast index (coalesced)
    const int q  = t >> 6;           // 0..3

    const float* fb = f + (size_t)b * NCH * NPTS;
#pragma unroll
    for (int r = 0; r < 16; ++r) {
        int c = r * 4 + q;
        tile[c][nl] = fb[(size_t)c * NPTS + n0 + nl];
    }
    __syncthreads();
    float* ftb = ft + ((size_t)b * NPTS + n0) * NCH;
#pragma unroll
    for (int r = 0; r < 16; ++r) {
        int n = r * 4 + q;
        ftb[(size_t)n * NCH + nl] = tile[nl][n];   // lanes: addr=nl*65+n -> 2-way max (free)
    }
}

// -------- Kernel 2: fused ball query + grouping. One wave per center. --------
__global__ __launch_bounds__(256) void ballquery_group(
    const float* __restrict__ points,   // (2,16384,3)
    const float* __restrict__ centers,  // (2,2048,3)
    const float* __restrict__ feats,    // (2,64,16384)  fallback path
    const float* __restrict__ featsT,   // (2,16384,64)  or nullptr
    float* __restrict__ out_xyz,        // (2,3,2048,32)
    float* __restrict__ out_feat)       // (2,64,2048,32)
{
#pragma clang fp contract(off)          // match numpy's step-rounded (no-FMA) d2
    __shared__ int   s_idx[4][KK];
    __shared__ float s_f[4][KK][65];    // pad 65: conflict-free in both phases

    const int wave = threadIdx.x >> 6;
    const int lane = threadIdx.x & 63;
    const int cg   = blockIdx.x * 4 + wave;   // 0..4095
    const int b    = cg >> 11;                // /2048
    const int g    = cg & (NCTR - 1);

    const float* pb = points + (size_t)b * NPTS * 3;
    const float* cc = centers + (size_t)cg * 3;
    const float cx = cc[0], cy = cc[1], cz = cc[2];
    const float c2 = (cx * cx + cy * cy) + cz * cz;

    int* idxs = s_idx[wave];

    // ---- ballot scan: first KK in-radius indices in ascending order ----
    int cnt = 0;
    for (int base = 0; base < NPTS; base += 64) {
        const int i = base + lane;
        const float px = pb[i * 3 + 0];
        const float py = pb[i * 3 + 1];
        const float pz = pb[i * 3 + 2];
        const float p2 = (px * px + py * py) + pz * pz;
        const float cp = (cx * px + cy * py) + cz * pz;
        const float d2 = (c2 + p2) - 2.0f * cp;
        const bool hit = d2 < R2;
        const unsigned long long m = __ballot(hit);
        if (hit) {
            const int slot = cnt + __popcll(m & ((1ull << lane) - 1ull));
            if (slot < KK) idxs[slot] = i;
        }
        cnt += (int)__popcll(m);
        if (cnt >= KK) break;     // wave-uniform (cnt from ballot)
    }
    __syncthreads();              // cross-lane LDS visibility (all waves reach once)

    // ---- pad: slots >= cnt get idxs[0] (or 0 if no hits) ----
    const int cpd = cnt < KK ? cnt : KK;
    const int first = (cnt > 0) ? idxs[0] : 0;
    if (lane < KK) {
        idxs[lane] = (lane < cpd) ? idxs[lane] : first;
    }
    __syncthreads();

    // ---- grouped_xyz: (p - c) / 0.2 ----
    if (lane < KK) {
        const int id = idxs[lane];
        const float px = pb[id * 3 + 0];
        const float py = pb[id * 3 + 1];
        const float pz = pb[id * 3 + 2];
        const size_t ob = (((size_t)b * 3 + 0) * NCTR + g) * KK + lane;
        out_xyz[ob + (size_t)0 * NCTR * KK] = (px - cx) / 0.2f;
        out_xyz[ob + (size_t)1 * NCTR * KK] = (py - cy) / 0.2f;
        out_xyz[ob + (size_t)2 * NCTR * KK] = (pz - cz) / 0.2f;
    }

    // ---- grouped_features: gather 64 channels x 32 ids ----
    float (*sf)[65] = s_f[wave];
    if (featsT) {
        // coalesced: one 256B row per id; lane = channel
        const float* ftb = featsT + (size_t)b * NPTS * NCH;
#pragma unroll 4
        for (int k = 0; k < KK; ++k) {
            const int id = idxs[k];
            sf[k][lane] = ftb[(size_t)id * NCH + lane];
        }
    } else {
        // fallback: strided reads (slow but correct)
        const float* fb = feats + (size_t)b * NCH * NPTS;
        for (int k = 0; k < KK; ++k) {
            const int id = idxs[k];
            sf[k][lane] = fb[(size_t)lane * NPTS + id];
        }
    }
    __syncthreads();

    // write phase: coalesced along k, two channels per iteration
    const int k  = lane & 31;
    const int ch = lane >> 5;
    const size_t ob = ((size_t)b * NCH * NCTR + g) * KK;
#pragma unroll
    for (int cc2 = 0; cc2 < 32; ++cc2) {
        const int c = cc2 * 2 + ch;
        out_feat[ob + (size_t)c * NCTR * KK + k] = sf[k][c];  // LDS: (65k+c)%32 distinct
    }
}

extern "C" void kernel_launch(void* const* d_in, const int* in_sizes, int n_in,
                              void* d_out, int out_size, void* d_ws, size_t ws_size,
                              hipStream_t stream) {
    const float* points  = (const float*)d_in[0];   // (2,16384,3)
    const float* centers = (const float*)d_in[1];   // (2,2048,3)
    const float* feats   = (const float*)d_in[2];   // (2,64,16384)

    float* out      = (float*)d_out;
    float* out_xyz  = out;                                    // (2,3,2048,32)
    float* out_feat = out + (size_t)NB * 3 * NCTR * KK;       // (2,64,2048,32)

    const size_t ftBytes = (size_t)NB * NPTS * NCH * sizeof(float);
    float* featsT = nullptr;
    if (ws_size >= ftBytes) {
        featsT = (float*)d_ws;
        transpose_feats<<<dim3(NPTS / 64, NB), 256, 0, stream>>>(feats, featsT);
    }

    // 4096 centers, 4 per block (one wave each)
    ballquery_group<<<(NB * NCTR) / 4, 256, 0, stream>>>(
        points, centers, feats, featsT, out_xyz, out_feat);
}

// Round 2
// 88.279 us; speedup vs baseline: 1.2555x; 1.2555x over previous
//
#include <hip/hip_runtime.h>
#include <hip/hip_bf16.h>

// Problem constants (fixed shapes from setup_inputs)
constexpr int NPTS = 16384;   // points per batch
constexpr int NCTR = 2048;    // centers per batch
constexpr int NCH  = 64;      // feature channels
constexpr int KK   = 32;      // neighbors per center
constexpr int NB   = 2;       // batches
// radius^2: reference compares d2 < fp32(0.04) (python double 0.2*0.2 -> f32)
#define R2 0.04f

// -------- Kernel 1: transpose features (b,64,16384) -> (b,16384,64) --------
__global__ __launch_bounds__(256) void transpose_feats(
    const float* __restrict__ f, float* __restrict__ ft)
{
    __shared__ float tile[64][65];   // +1 pad: conflict-free transpose
    const int b  = blockIdx.y;
    const int n0 = blockIdx.x * 64;
    const int t  = threadIdx.x;
    const int nl = t & 63;           // fast index (coalesced)
    const int q  = t >> 6;           // 0..3

    const float* fb = f + (size_t)b * NCH * NPTS;
#pragma unroll
    for (int r = 0; r < 16; ++r) {
        int c = r * 4 + q;
        tile[c][nl] = fb[(size_t)c * NPTS + n0 + nl];
    }
    __syncthreads();
    float* ftb = ft + ((size_t)b * NPTS + n0) * NCH;
#pragma unroll
    for (int r = 0; r < 16; ++r) {
        int n = r * 4 + q;
        ftb[(size_t)n * NCH + nl] = tile[nl][n];   // lanes: addr=nl*65+n -> 2-way max (free)
    }
}

// -------- Kernel 2: fused ball query + grouping. One wave per center. --------
// Scan restructured vs R1: 512-point chunks, 24 independent loads grouped,
// next chunk prefetched into registers before processing current (latency
// chain was the R1 bottleneck: tail waves scanned 100-256 serial 64-pt iters).
__global__ __launch_bounds__(256) void ballquery_group(
    const float* __restrict__ points,   // (2,16384,3)
    const float* __restrict__ centers,  // (2,2048,3)
    const float* __restrict__ feats,    // (2,64,16384)  fallback path
    const float* __restrict__ featsT,   // (2,16384,64)  or nullptr
    float* __restrict__ out_xyz,        // (2,3,2048,32)
    float* __restrict__ out_feat)       // (2,64,2048,32)
{
#pragma clang fp contract(off)          // match numpy's step-rounded (no-FMA) d2 EXACTLY (R1: absmax=0)
    __shared__ int   s_idx[4][KK];
    __shared__ float s_f[4][KK][65];    // pad 65: conflict-free in both phases

    const int wave = threadIdx.x >> 6;
    const int lane = threadIdx.x & 63;
    const int cg   = blockIdx.x * 4 + wave;   // 0..4095
    const int b    = cg >> 11;                // /2048
    const int g    = cg & (NCTR - 1);

    const float* pb = points + (size_t)b * NPTS * 3;
    const float* cc = centers + (size_t)cg * 3;
    const float cx = cc[0], cy = cc[1], cz = cc[2];
    const float c2 = (cx * cx + cy * cy) + cz * cz;

    int* idxs = s_idx[wave];

    // ---- chunked ballot scan: first KK in-radius indices, ascending ----
    float x[8], y[8], z[8], nx[8], ny[8], nz[8];
#pragma unroll
    for (int j = 0; j < 8; ++j) {             // prefetch chunk 0
        const int i = j * 64 + lane;
        x[j] = pb[i * 3 + 0]; y[j] = pb[i * 3 + 1]; z[j] = pb[i * 3 + 2];
    }
    int cnt = 0;
    for (int base = 0; base < NPTS; base += 512) {
        // prefetch next chunk (wrap to 0 at end: loaded but never processed)
        const int nb = (base + 512 < NPTS) ? base + 512 : 0;
#pragma unroll
        for (int j = 0; j < 8; ++j) {
            const int i = nb + j * 64 + lane;
            nx[j] = pb[i * 3 + 0]; ny[j] = pb[i * 3 + 1]; nz[j] = pb[i * 3 + 2];
        }
        // process current chunk: 8 ordered sub-ballots
#pragma unroll
        for (int j = 0; j < 8; ++j) {
            const float p2 = (x[j] * x[j] + y[j] * y[j]) + z[j] * z[j];
            const float cp = (cx * x[j] + cy * y[j]) + cz * z[j];
            const float d2 = (c2 + p2) - 2.0f * cp;
            const bool hit = d2 < R2;
            const unsigned long long m = __ballot(hit);
            if (hit) {
                const int slot = cnt + __popcll(m & ((1ull << lane) - 1ull));
                if (slot < KK) idxs[slot] = base + j * 64 + lane;
            }
            cnt += (int)__popcll(m);
        }
        if (cnt >= KK) break;                 // wave-uniform (cnt from ballot)
#pragma unroll
        for (int j = 0; j < 8; ++j) { x[j] = nx[j]; y[j] = ny[j]; z[j] = nz[j]; }
    }
    __syncthreads();              // cross-lane LDS visibility (all waves reach once)

    // ---- pad: slots >= cnt get idxs[0] (or 0 if no hits) ----
    const int cpd = cnt < KK ? cnt : KK;
    const int first = (cnt > 0) ? idxs[0] : 0;
    if (lane < KK) {
        idxs[lane] = (lane < cpd) ? idxs[lane] : first;
    }
    __syncthreads();

    // ---- grouped_xyz: (p - c) / 0.2 ----
    if (lane < KK) {
        const int id = idxs[lane];
        const float px = pb[id * 3 + 0];
        const float py = pb[id * 3 + 1];
        const float pz = pb[id * 3 + 2];
        const size_t ob = (((size_t)b * 3 + 0) * NCTR + g) * KK + lane;
        out_xyz[ob + (size_t)0 * NCTR * KK] = (px - cx) / 0.2f;
        out_xyz[ob + (size_t)1 * NCTR * KK] = (py - cy) / 0.2f;
        out_xyz[ob + (size_t)2 * NCTR * KK] = (pz - cz) / 0.2f;
    }

    // ---- grouped_features: gather 64 channels x 32 ids ----
    float (*sf)[65] = s_f[wave];
    if (featsT) {
        // coalesced: one 256B row per id; lane = channel; 8 rows in flight
        const float* ftb = featsT + (size_t)b * NPTS * NCH;
#pragma unroll 8
        for (int k = 0; k < KK; ++k) {
            const int id = idxs[k];
            sf[k][lane] = ftb[(size_t)id * NCH + lane];
        }
    } else {
        // fallback: strided reads (slow but correct)
        const float* fb = feats + (size_t)b * NCH * NPTS;
        for (int k = 0; k < KK; ++k) {
            const int id = idxs[k];
            sf[k][lane] = fb[(size_t)lane * NPTS + id];
        }
    }
    __syncthreads();

    // write phase: coalesced along k, two channels per iteration
    const int k  = lane & 31;
    const int ch = lane >> 5;
    const size_t ob = ((size_t)b * NCH * NCTR + g) * KK;
#pragma unroll
    for (int cc2 = 0; cc2 < 32; ++cc2) {
        const int c = cc2 * 2 + ch;
        out_feat[ob + (size_t)c * NCTR * KK + k] = sf[k][c];  // LDS: (65k+c)%32 distinct
    }
}

extern "C" void kernel_launch(void* const* d_in, const int* in_sizes, int n_in,
                              void* d_out, int out_size, void* d_ws, size_t ws_size,
                              hipStream_t stream) {
    const float* points  = (const float*)d_in[0];   // (2,16384,3)
    const float* centers = (const float*)d_in[1];   // (2,2048,3)
    const float* feats   = (const float*)d_in[2];   // (2,64,16384)

    float* out      = (float*)d_out;
    float* out_xyz  = out;                                    // (2,3,2048,32)
    float* out_feat = out + (size_t)NB * 3 * NCTR * KK;       // (2,64,2048,32)

    const size_t ftBytes = (size_t)NB * NPTS * NCH * sizeof(float);
    float* featsT = nullptr;
    if (ws_size >= ftBytes) {
        featsT = (float*)d_ws;
        transpose_feats<<<dim3(NPTS / 64, NB), 256, 0, stream>>>(feats, featsT);
    }

    // 4096 centers, 4 per block (one wave each)
    ballquery_group<<<(NB * NCTR) / 4, 256, 0, stream>>>(
        points, centers, feats, featsT, out_xyz, out_feat);
}